// Round 4
// baseline (457.991 us; speedup 1.0000x reference)
//
#include <hip/hip_runtime.h>
#include <math.h>

#define B_ROWS 16384
#define IN_DIM 784
#define OUT_DIM 100
#define NITER 50

#define TB  512          // 8 waves
#define RPB 64           // rows per block -> grid 256
#define NPAD 112         // 7 n-tiles of 16
#define KPAD 128         // 4 k-chunks of 32

typedef float  f32x4  __attribute__((ext_vector_type(4)));
typedef short  short8 __attribute__((ext_vector_type(8)));
typedef unsigned int uint4v __attribute__((ext_vector_type(4)));

#define MFMA16 __builtin_amdgcn_mfma_f32_16x16x32_bf16

// ---- LDS byte map (dynamic, 139264 B total) ----
#define WH_OFF   0            // W_hi  [112][128] bf16, swizzled
#define WL_OFF   28672        // W_lo
#define ZP_OFF   57344        // z     [64][128] bf16, swizzled
#define SH_OFF   73728        // s_hi
#define SL_OFF   90112        // s_lo
#define DH_OFF   106496       // d_hi
#define DL_OFF   122880       // d_lo
#define LDS_TOTAL 139264
// injection staging overlays the state region (states not live yet)
#define XB_OFF  57344         // x  tile  [64][40] bf16
#define XS_OFF  62464        // xs tile
#define XD_OFF  67584        // xd tile
#define UB_OFF  73728        // U  tile  [112][40] bf16
#define AU_OFF  82688        // |U| tile

__device__ __forceinline__ unsigned enc_f(float f) {
  unsigned u = __float_as_uint(f);
  return (u & 0x80000000u) ? ~u : (u | 0x80000000u);
}
__device__ __forceinline__ float dec_f(unsigned e) {
  unsigned u = (e & 0x80000000u) ? (e ^ 0x80000000u) : ~e;
  return __uint_as_float(u);
}
__device__ __forceinline__ unsigned short bf16t(float f) {
  return (unsigned short)(__float_as_uint(f) >> 16);
}
// pack hi16(f1):hi16(f0) into one u32 (two bf16 lanes; f0 -> low half)
__device__ __forceinline__ unsigned pk(float f1, float f0) {
  return __builtin_amdgcn_perm(__float_as_uint(f1), __float_as_uint(f0), 0x07060302u);
}

__global__ void k_init(unsigned* wsu) {
  wsu[0] = 0u;
  wsu[1] = 0xFFFFFFFFu;
}

__global__ void k_minmax(const float4* __restrict__ x4, unsigned* __restrict__ wsu) {
  float mx = -3.4e38f, mn = 3.4e38f;
  const int n4 = (B_ROWS * IN_DIM) / 4;
  for (int i = blockIdx.x * blockDim.x + threadIdx.x; i < n4; i += gridDim.x * blockDim.x) {
    float4 v = x4[i];
    mx = fmaxf(mx, fmaxf(fmaxf(v.x, v.y), fmaxf(v.z, v.w)));
    mn = fminf(mn, fminf(fminf(v.x, v.y), fminf(v.z, v.w)));
  }
  #pragma unroll
  for (int o = 32; o; o >>= 1) {
    mx = fmaxf(mx, __shfl_xor(mx, o));
    mn = fminf(mn, __shfl_xor(mn, o));
  }
  __shared__ float smx[8], smn[8];
  int wid = threadIdx.x >> 6;
  if ((threadIdx.x & 63) == 0) { smx[wid] = mx; smn[wid] = mn; }
  __syncthreads();
  if (threadIdx.x == 0) {
    int nw = blockDim.x >> 6;
    for (int w = 1; w < nw; ++w) { mx = fmaxf(mx, smx[w]); mn = fminf(mn, smn[w]); }
    atomicMax(&wsu[0], enc_f(mx));
    atomicMin(&wsu[1], enc_f(mn));
  }
}

__global__ void k_wbuild(const float* __restrict__ A, float* __restrict__ Wout) {
  int c = threadIdx.x;
  if (c < OUT_DIM) {
    float T = 0.f;
    for (int j = 0; j < OUT_DIM; ++j)
      if (j != c) T += fabsf(A[c * OUT_DIM + j]);
    for (int j = 0; j < OUT_DIM; ++j)
      Wout[c * OUT_DIM + j] = (j == c) ? (0.9f - T) : A[c * OUT_DIM + j];
  }
}

__launch_bounds__(TB, 1)
__global__ void k_main(const float* __restrict__ x, const float* __restrict__ epsp,
                       const float* __restrict__ bvec, const float* __restrict__ Wws,
                       const unsigned* __restrict__ wsu, const float* __restrict__ U,
                       float* __restrict__ out) {
  extern __shared__ char lds[];
  const int t    = threadIdx.x;
  const int lane = t & 63;
  const int w    = t >> 6;          // wave 0..7
  const int g    = lane >> 4;       // lane-group 0..3
  const int q15  = lane & 15;
  const int mt   = w & 3;           // m-tile (16 rows)
  const int nh   = w >> 2;          // n-half
  const int NTW  = nh ? 3 : 4;      // n-tiles for this wave
  const int r0   = blockIdx.x * RPB;
  const int mrow = mt * 16 + q15;   // state row this lane reads/owns (B-frag)
  const int swl  = q15 & 7;

  // ---- pack W into bf16 hi/lo swizzled planes ----
  for (int e = t; e < NPAD * KPAD; e += TB) {
    int n = e >> 7, k = e & 127;
    float wv = (n < OUT_DIM && k < OUT_DIM) ? Wws[n * OUT_DIM + k] : 0.f;
    unsigned u = __float_as_uint(wv);
    float hif = __uint_as_float(u & 0xffff0000u);
    int byte = n * 256 + ((((k >> 3) ^ (n & 7))) << 4) + (k & 7) * 2;
    *(unsigned short*)(lds + WH_OFF + byte) = (unsigned short)(u >> 16);
    *(unsigned short*)(lds + WL_OFF + byte) = bf16t(wv - hif);
  }

  const float eps  = epsp[0];
  const float xmax = dec_f(wsu[0]);
  const float xmin = dec_f(wsu[1]);

  // ---- injection accumulators (D layout: row n = ntile+g*4+r, col m = q15) ----
  f32x4 inj_u[4], inj_s[4], inj_d[4];
  #pragma unroll
  for (int q = 0; q < 4; ++q) {
    #pragma unroll
    for (int r = 0; r < 4; ++r) {
      int n = nh * 64 + q * 16 + g * 4 + r;
      float bn = (q < NTW && n < OUT_DIM) ? bvec[n] : 0.f;
      inj_u[q][r] = bn; inj_s[q][r] = bn; inj_d[q][r] = 0.f;
    }
  }

  // ---- injection: 25 chunks of K=32 over IN_DIM=784 (pad 800) ----
  for (int kb = 0; kb < 25; ++kb) {
    __syncthreads();
    { // stage x tile [64][32] -> x, xs, xd bf16 planes [64][40]
      int row = t >> 3, k4 = t & 7;
      float4 xv;
      if (kb == 24 && k4 >= 4) xv = make_float4(0.f, 0.f, 0.f, 0.f);
      else xv = *(const float4*)(x + (size_t)(r0 + row) * IN_DIM + kb * 32 + k4 * 4);
      float xh0 = fminf(xv.x + eps, xmax), xl0 = fmaxf(xv.x - eps, xmin);
      float xh1 = fminf(xv.y + eps, xmax), xl1 = fmaxf(xv.y - eps, xmin);
      float xh2 = fminf(xv.z + eps, xmax), xl2 = fmaxf(xv.z - eps, xmin);
      float xh3 = fminf(xv.w + eps, xmax), xl3 = fmaxf(xv.w - eps, xmin);
      int byte = row * 80 + k4 * 8;
      *(uint2*)(lds + XB_OFF + byte) = make_uint2(pk(xv.y, xv.x), pk(xv.w, xv.z));
      *(uint2*)(lds + XS_OFF + byte) =
          make_uint2(pk(0.5f * (xh1 + xl1), 0.5f * (xh0 + xl0)),
                     pk(0.5f * (xh3 + xl3), 0.5f * (xh2 + xl2)));
      *(uint2*)(lds + XD_OFF + byte) =
          make_uint2(pk(0.5f * (xh1 - xl1), 0.5f * (xh0 - xl0)),
                     pk(0.5f * (xh3 - xl3), 0.5f * (xh2 - xl2)));
    }
    #pragma unroll
    for (int p = 0; p < 2; ++p) {
      int e = t + p * TB;
      if (e < NPAD * 8) {
        int c = e >> 3, k4 = e & 7;
        float4 uv;
        if (c >= OUT_DIM || (kb == 24 && k4 >= 4)) uv = make_float4(0.f, 0.f, 0.f, 0.f);
        else uv = *(const float4*)(U + (size_t)c * IN_DIM + kb * 32 + k4 * 4);
        int byte = c * 80 + k4 * 8;
        *(uint2*)(lds + UB_OFF + byte) = make_uint2(pk(uv.y, uv.x), pk(uv.w, uv.z));
        *(uint2*)(lds + AU_OFF + byte) =
            make_uint2(pk(fabsf(uv.y), fabsf(uv.x)), pk(fabsf(uv.w), fabsf(uv.z)));
      }
    }
    __syncthreads();
    { // MFMA accumulate this chunk: A = U-frag, B = x-frag
      int sa = mrow * 80 + g * 16;
      short8 xa  = *(const short8*)(lds + XB_OFF + sa);
      short8 xsa = *(const short8*)(lds + XS_OFF + sa);
      short8 xda = *(const short8*)(lds + XD_OFF + sa);
      #pragma unroll
      for (int q = 0; q < 4; ++q) if (q < NTW) {
        int sb = (nh * 64 + q * 16 + q15) * 80 + g * 16;
        short8 ub = *(const short8*)(lds + UB_OFF + sb);
        short8 ab = *(const short8*)(lds + AU_OFF + sb);
        inj_u[q] = MFMA16(ub, xa,  inj_u[q], 0, 0, 0);
        inj_s[q] = MFMA16(ub, xsa, inj_s[q], 0, 0, 0);
        inj_d[q] = MFMA16(ab, xda, inj_d[q], 0, 0, 0);
      }
    }
  }

  // ---- register-cache W fragments for kc = 0,1 ----
  short8 wch[2][4], wcl[2][4];
  #pragma unroll
  for (int kc = 0; kc < 2; ++kc) {
    #pragma unroll
    for (int q = 0; q < 4; ++q) if (q < NTW) {
      int wo = (nh * 64 + q * 16 + q15) * 256 + (((kc * 4 + g) ^ swl) << 4);
      wch[kc][q] = *(const short8*)(lds + WH_OFF + wo);
      wcl[kc][q] = *(const short8*)(lds + WL_OFF + wo);
    }
  }

  // ---- zero state planes ----
  __syncthreads();
  for (int e = t * 16; e < LDS_TOTAL - ZP_OFF; e += TB * 16)
    *(f32x4*)(lds + ZP_OFF + e) = (f32x4){0.f, 0.f, 0.f, 0.f};
  __syncthreads();

  f32x4 zc[4], sc[4], dc[4];
  #pragma unroll
  for (int q = 0; q < 4; ++q) {
    zc[q] = (f32x4){0.f, 0.f, 0.f, 0.f};
    sc[q] = (f32x4){0.f, 0.f, 0.f, 0.f};
    dc[q] = (f32x4){0.f, 0.f, 0.f, 0.f};
  }

  // ---- 50 fixed-point iterations ----
  for (int it = 0; it < NITER; ++it) {
    f32x4 az[4], as4[4], ad4[4];

    #pragma unroll
    for (int kc = 0; kc < 4; ++kc) {
      const int so = mrow * 256 + (((kc * 4 + g) ^ swl) << 4);
      short8 z8  = *(const short8*)(lds + ZP_OFF + so);
      short8 sh8 = *(const short8*)(lds + SH_OFF + so);
      short8 sl8 = *(const short8*)(lds + SL_OFF + so);
      short8 dh8 = *(const short8*)(lds + DH_OFF + so);
      short8 dl8 = *(const short8*)(lds + DL_OFF + so);
      #pragma unroll
      for (int q = 0; q < 4; ++q) if (q < NTW) {
        short8 wh, wl;
        if (kc < 2) { wh = wch[kc][q]; wl = wcl[kc][q]; }
        else {
          int wo = (nh * 64 + q * 16 + q15) * 256 + (((kc * 4 + g) ^ swl) << 4);
          wh = *(const short8*)(lds + WH_OFF + wo);
          wl = *(const short8*)(lds + WL_OFF + wo);
        }
        uint4v whu  = __builtin_bit_cast(uint4v, wh);
        uint4v awhu = whu & 0x7fff7fffu;
        uint4v awlu = __builtin_bit_cast(uint4v, wl) ^ (whu & 0x80008000u);
        short8 awh = __builtin_bit_cast(short8, awhu);
        short8 awl = __builtin_bit_cast(short8, awlu);
        if (kc == 0) {
          az[q]  = MFMA16(wh,  z8,  inj_u[q], 0, 0, 0);
          as4[q] = MFMA16(wh,  sh8, inj_s[q], 0, 0, 0);
          as4[q] = MFMA16(wl,  sh8, as4[q],   0, 0, 0);
          as4[q] = MFMA16(wh,  sl8, as4[q],   0, 0, 0);
          ad4[q] = MFMA16(awh, dh8, inj_d[q], 0, 0, 0);
          ad4[q] = MFMA16(awl, dh8, ad4[q],   0, 0, 0);
          ad4[q] = MFMA16(awh, dl8, ad4[q],   0, 0, 0);
        } else {
          az[q]  = MFMA16(wh,  z8,  az[q],  0, 0, 0);
          as4[q] = MFMA16(wh,  sh8, as4[q], 0, 0, 0);
          as4[q] = MFMA16(wl,  sh8, as4[q], 0, 0, 0);
          as4[q] = MFMA16(wh,  sl8, as4[q], 0, 0, 0);
          ad4[q] = MFMA16(awh, dh8, ad4[q], 0, 0, 0);
          ad4[q] = MFMA16(awl, dh8, ad4[q], 0, 0, 0);
          ad4[q] = MFMA16(awh, dl8, ad4[q], 0, 0, 0);
        }
      }
    }

    // update (registers only)
    #pragma unroll
    for (int q = 0; q < 4; ++q) if (q < NTW) {
      #pragma unroll
      for (int c = 0; c < 4; ++c) {
        float zn = fmaxf(az[q][c], 0.f);
        zc[q][c] = 0.5f * zc[q][c] + 0.5f * zn;
        float rp = fmaxf(as4[q][c] + ad4[q][c], 0.f);
        float rm = fmaxf(as4[q][c] - ad4[q][c], 0.f);
        sc[q][c] = 0.5f * sc[q][c] + 0.25f * (rp + rm);
        dc[q][c] = 0.5f * dc[q][c] + 0.25f * (rp - rm);
      }
    }

    if (it < NITER - 1) {
      __syncthreads();   // all frag reads done before overwrite
      #pragma unroll
      for (int q = 0; q < 4; ++q) if (q < NTW) {
        // this lane writes row mrow, cols n0..n0+3 (8 contiguous bytes/plane)
        const int slot = (nh * 8 + q * 2 + (g >> 1)) ^ swl;
        const int wb = mrow * 256 + (slot << 4) + (g & 1) * 8;
        *(uint2*)(lds + ZP_OFF + wb) =
            make_uint2(pk(zc[q][1], zc[q][0]), pk(zc[q][3], zc[q][2]));
        f32x4 shi, slo;
        #pragma unroll
        for (int c = 0; c < 4; ++c) {
          shi[c] = __uint_as_float(__float_as_uint(sc[q][c]) & 0xffff0000u);
          slo[c] = sc[q][c] - shi[c];
        }
        *(uint2*)(lds + SH_OFF + wb) =
            make_uint2(pk(shi[1], shi[0]), pk(shi[3], shi[2]));
        *(uint2*)(lds + SL_OFF + wb) =
            make_uint2(pk(slo[1], slo[0]), pk(slo[3], slo[2]));
        f32x4 dhi, dlo;
        #pragma unroll
        for (int c = 0; c < 4; ++c) {
          dhi[c] = __uint_as_float(__float_as_uint(dc[q][c]) & 0xffff0000u);
          dlo[c] = dc[q][c] - dhi[c];
        }
        *(uint2*)(lds + DH_OFF + wb) =
            make_uint2(pk(dhi[1], dhi[0]), pk(dhi[3], dhi[2]));
        *(uint2*)(lds + DL_OFF + wb) =
            make_uint2(pk(dlo[1], dlo[0]), pk(dlo[3], dlo[2]));
      }
      __syncthreads();   // writes visible before next iteration's reads
    }
  }

  // ---- store out: z / zh=s+d / zl=s-d (dwordx4 per tile) ----
  const int PL = B_ROWS * OUT_DIM;
  #pragma unroll
  for (int q = 0; q < 4; ++q) if (q < NTW) {
    const int n0 = nh * 64 + q * 16 + g * 4;
    if (n0 < OUT_DIM) {   // n0 multiple of 4; 100 % 4 == 0 so full vectors only
      const int gi = (r0 + mrow) * OUT_DIM + n0;
      f32x4 zh_, zl_;
      #pragma unroll
      for (int c = 0; c < 4; ++c) {
        zh_[c] = sc[q][c] + dc[q][c];
        zl_[c] = sc[q][c] - dc[q][c];
      }
      *(f32x4*)(out + gi)          = zc[q];
      *(f32x4*)(out + PL + gi)     = zh_;
      *(f32x4*)(out + 2 * PL + gi) = zl_;
    }
  }
}

extern "C" void kernel_launch(void* const* d_in, const int* in_sizes, int n_in,
                              void* d_out, int out_size, void* d_ws, size_t ws_size,
                              hipStream_t stream) {
  const float* x   = (const float*)d_in[0];
  const float* eps = (const float*)d_in[1];
  const float* A   = (const float*)d_in[2];
  const float* U   = (const float*)d_in[3];
  const float* b   = (const float*)d_in[4];
  float* out = (float*)d_out;

  unsigned* wsu = (unsigned*)d_ws;
  float* Wws = (float*)d_ws + 16;

  (void)hipFuncSetAttribute((const void*)k_main,
                            hipFuncAttributeMaxDynamicSharedMemorySize, LDS_TOTAL);

  k_init<<<1, 1, 0, stream>>>(wsu);
  k_minmax<<<1024, 256, 0, stream>>>((const float4*)x, wsu);
  k_wbuild<<<1, 128, 0, stream>>>(A, Wws);
  k_main<<<B_ROWS / RPB, TB, LDS_TOTAL, stream>>>(x, eps, b, Wws, wsu, U, out);
}

// Round 5
// 289.091 us; speedup vs baseline: 1.5842x; 1.5842x over previous
//
#include <hip/hip_runtime.h>
#include <math.h>

#define B_ROWS 16384
#define IN_DIM 784
#define OUT_DIM 100
#define NITER 50

#define TB  512          // 8 waves: 2 m-tiles x 4 n-tiles of 32x32
#define RPB 64           // rows per block -> grid 256
#define WKP 112          // padded K for W (7 chunks of 16)

typedef float  f32x4   __attribute__((ext_vector_type(4)));
typedef float  f32x16  __attribute__((ext_vector_type(16)));
typedef short  short8  __attribute__((ext_vector_type(8)));
typedef unsigned int uint4v __attribute__((ext_vector_type(4)));

#define MFMA32 __builtin_amdgcn_mfma_f32_32x32x16_bf16

// ---- LDS: 5 state planes [64 rows][128 K] bf16, slot-swizzled ----
#define ZP_OFF 0
#define SH_OFF 16384
#define SL_OFF 32768
#define DH_OFF 49152
#define DL_OFF 65536
#define LDS_TOTAL 81920

// ---- workspace layout (floats) ----
// [0..15]   minmax header (u32)
// [16 ..)   Wpad [128][112]  (rows>=100 and k>=100 zeroed)
// [16+14336 ..) Upad [128][784] (rows>=100 zeroed)
#define WPAD_F 16
#define UPAD_F (16 + 128 * WKP)

__device__ __forceinline__ unsigned enc_f(float f) {
  unsigned u = __float_as_uint(f);
  return (u & 0x80000000u) ? ~u : (u | 0x80000000u);
}
__device__ __forceinline__ float dec_f(unsigned e) {
  unsigned u = (e & 0x80000000u) ? (e ^ 0x80000000u) : ~e;
  return __uint_as_float(u);
}
// pack hi16(f1):hi16(f0) -> u32 (f0 in low half)
__device__ __forceinline__ unsigned pk(float f1, float f0) {
  return __builtin_amdgcn_perm(__float_as_uint(f1), __float_as_uint(f0), 0x07060302u);
}
__device__ __forceinline__ short8 pack8(f32x4 a, f32x4 b) {
  uint4v u;
  u[0] = pk(a[1], a[0]); u[1] = pk(a[3], a[2]);
  u[2] = pk(b[1], b[0]); u[3] = pk(b[3], b[2]);
  return __builtin_bit_cast(short8, u);
}

__global__ void k_init(unsigned* wsu) {
  wsu[0] = 0u;
  wsu[1] = 0xFFFFFFFFu;
}

__global__ void k_minmax(const float4* __restrict__ x4, unsigned* __restrict__ wsu) {
  float mx = -3.4e38f, mn = 3.4e38f;
  const int n4 = (B_ROWS * IN_DIM) / 4;
  for (int i = blockIdx.x * blockDim.x + threadIdx.x; i < n4; i += gridDim.x * blockDim.x) {
    float4 v = x4[i];
    mx = fmaxf(mx, fmaxf(fmaxf(v.x, v.y), fmaxf(v.z, v.w)));
    mn = fminf(mn, fminf(fminf(v.x, v.y), fminf(v.z, v.w)));
  }
  #pragma unroll
  for (int o = 32; o; o >>= 1) {
    mx = fmaxf(mx, __shfl_xor(mx, o));
    mn = fminf(mn, __shfl_xor(mn, o));
  }
  __shared__ float smx[8], smn[8];
  int wid = threadIdx.x >> 6;
  if ((threadIdx.x & 63) == 0) { smx[wid] = mx; smn[wid] = mn; }
  __syncthreads();
  if (threadIdx.x == 0) {
    int nw = blockDim.x >> 6;
    for (int w = 1; w < nw; ++w) { mx = fmaxf(mx, smx[w]); mn = fminf(mn, smn[w]); }
    atomicMax(&wsu[0], enc_f(mx));
    atomicMin(&wsu[1], enc_f(mn));
  }
}

// Wpad[128][112]: W = offdiag(A) + diag(0.9 - sum|offdiag|), zero-padded
__global__ void k_wbuild(const float* __restrict__ A, float* __restrict__ Wpad) {
  int c = threadIdx.x;   // 128 threads
  if (c < OUT_DIM) {
    float T = 0.f;
    for (int j = 0; j < OUT_DIM; ++j)
      if (j != c) T += fabsf(A[c * OUT_DIM + j]);
    for (int k = 0; k < WKP; ++k) {
      float v = 0.f;
      if (k < OUT_DIM) v = (k == c) ? (0.9f - T) : A[c * OUT_DIM + k];
      Wpad[c * WKP + k] = v;
    }
  } else if (c < 128) {
    for (int k = 0; k < WKP; ++k) Wpad[c * WKP + k] = 0.f;
  }
}

// Upad[128][784]: rows >= 100 zeroed
__global__ void k_upad(const float* __restrict__ U, float* __restrict__ Upad) {
  int i = blockIdx.x * blockDim.x + threadIdx.x;
  if (i < 128 * IN_DIM) {
    int n = i / IN_DIM;
    Upad[i] = (n < OUT_DIM) ? ((n < OUT_DIM) ? U[i] : 0.f) : 0.f;
  }
}

__launch_bounds__(TB, 1)
__global__ void k_main(const float* __restrict__ x, const float* __restrict__ epsp,
                       const float* __restrict__ bvec, const float* __restrict__ Wpad,
                       const unsigned* __restrict__ wsu, const float* __restrict__ Upad,
                       float* __restrict__ out) {
  extern __shared__ char lds[];
  const int t    = threadIdx.x;
  const int l    = t & 63;
  const int w    = t >> 6;          // wave 0..7
  const int mt   = w >> 2;          // m-tile (32 rows)
  const int nt   = w & 3;           // n-tile (32 cols)
  const int lm   = l & 31;
  const int hi   = l >> 5;
  const int r0   = blockIdx.x * RPB;
  const int mrow = mt * 32 + lm;    // local batch row 0..63
  const int nbase = nt * 32;

  // ---- load W panel into registers (hi/lo split), once ----
  short8 whc[7], wlc[7];
  #pragma unroll
  for (int c = 0; c < 7; ++c) {
    const float* wp = Wpad + (nbase + lm) * WKP + c * 16 + hi * 8;
    f32x4 a = *(const f32x4*)wp;
    f32x4 b = *(const f32x4*)(wp + 4);
    whc[c] = pack8(a, b);
    f32x4 alo, blo;
    #pragma unroll
    for (int j = 0; j < 4; ++j) {
      alo[j] = a[j] - __uint_as_float(__float_as_uint(a[j]) & 0xffff0000u);
      blo[j] = b[j] - __uint_as_float(__float_as_uint(b[j]) & 0xffff0000u);
    }
    wlc[c] = pack8(alo, blo);
  }

  // ---- zero state planes, sync once ----
  for (int e = t * 16; e < LDS_TOTAL; e += TB * 16)
    *(f32x4*)(lds + e) = (f32x4){0.f, 0.f, 0.f, 0.f};
  __syncthreads();

  const float eps  = epsp[0];
  const float xmax = dec_f(wsu[0]);
  const float xmin = dec_f(wsu[1]);

  // ---- injection accumulators: D[n][m], n=(r&3)+8*(r>>2)+4*hi, m=lm ----
  f32x16 inj_u, inj_s, inj_d;
  #pragma unroll
  for (int r = 0; r < 16; ++r) {
    int n = nbase + (r & 3) + 8 * (r >> 2) + 4 * hi;
    float bn = (n < OUT_DIM) ? bvec[n] : 0.f;
    inj_u[r] = bn; inj_s[r] = bn; inj_d[r] = 0.f;
  }

  // ---- injection: 49 chunks of K=16, straight from global ----
  for (int c = 0; c < 49; ++c) {
    const int koff = c * 16 + hi * 8;
    const float* xp = x + (size_t)(r0 + mrow) * IN_DIM + koff;
    f32x4 x0 = *(const f32x4*)xp;
    f32x4 x1 = *(const f32x4*)(xp + 4);
    f32x4 xs0, xs1, xd0, xd1;
    #pragma unroll
    for (int j = 0; j < 4; ++j) {
      float h0 = fminf(x0[j] + eps, xmax), l0 = fmaxf(x0[j] - eps, xmin);
      float h1 = fminf(x1[j] + eps, xmax), l1 = fmaxf(x1[j] - eps, xmin);
      xs0[j] = 0.5f * (h0 + l0); xd0[j] = 0.5f * (h0 - l0);
      xs1[j] = 0.5f * (h1 + l1); xd1[j] = 0.5f * (h1 - l1);
    }
    short8 xa  = pack8(x0, x1);
    short8 xsa = pack8(xs0, xs1);
    short8 xda = pack8(xd0, xd1);

    const float* up = Upad + (size_t)(nbase + lm) * IN_DIM + koff;
    f32x4 u0 = *(const f32x4*)up;
    f32x4 u1 = *(const f32x4*)(up + 4);
    short8 ub = pack8(u0, u1);
    short8 au = __builtin_bit_cast(short8,
        __builtin_bit_cast(uint4v, ub) & 0x7fff7fffu);

    inj_u = MFMA32(ub, xa,  inj_u, 0, 0, 0);
    inj_s = MFMA32(ub, xsa, inj_s, 0, 0, 0);
    inj_d = MFMA32(au, xda, inj_d, 0, 0, 0);
  }

  f32x16 zc, sc, dc;
  #pragma unroll
  for (int r = 0; r < 16; ++r) { zc[r] = 0.f; sc[r] = 0.f; dc[r] = 0.f; }

  const int sw7 = mrow & 7;
  const int sbase = mrow * 256;

  // ---- 50 fixed-point iterations ----
  for (int it = 0; it < NITER; ++it) {
    // pass 1: z  (fold immediately to keep transient accum small)
    {
      f32x16 az = inj_u;
      #pragma unroll
      for (int c = 0; c < 7; ++c) {
        const int so = sbase + (((c * 2 + hi) ^ sw7) << 4);
        short8 z8 = *(const short8*)(lds + ZP_OFF + so);
        az = MFMA32(whc[c], z8, az, 0, 0, 0);
      }
      #pragma unroll
      for (int r = 0; r < 16; ++r)
        zc[r] = 0.5f * zc[r] + 0.5f * fmaxf(az[r], 0.f);
    }
    // pass 2: s and d
    {
      f32x16 as4 = inj_s, ad4 = inj_d;
      #pragma unroll
      for (int c = 0; c < 7; ++c) {
        const int so = sbase + (((c * 2 + hi) ^ sw7) << 4);
        short8 sh8 = *(const short8*)(lds + SH_OFF + so);
        short8 sl8 = *(const short8*)(lds + SL_OFF + so);
        short8 dh8 = *(const short8*)(lds + DH_OFF + so);
        short8 dl8 = *(const short8*)(lds + DL_OFF + so);
        short8 wh = whc[c], wl = wlc[c];
        uint4v whu = __builtin_bit_cast(uint4v, wh);
        short8 awh = __builtin_bit_cast(short8, whu & 0x7fff7fffu);
        short8 awl = __builtin_bit_cast(short8,
            __builtin_bit_cast(uint4v, wl) ^ (whu & 0x80008000u));
        as4 = MFMA32(wh,  sh8, as4, 0, 0, 0);
        as4 = MFMA32(wl,  sh8, as4, 0, 0, 0);
        as4 = MFMA32(wh,  sl8, as4, 0, 0, 0);
        ad4 = MFMA32(awh, dh8, ad4, 0, 0, 0);
        ad4 = MFMA32(awl, dh8, ad4, 0, 0, 0);
        ad4 = MFMA32(awh, dl8, ad4, 0, 0, 0);
      }
      #pragma unroll
      for (int r = 0; r < 16; ++r) {
        float rp = fmaxf(as4[r] + ad4[r], 0.f);
        float rm = fmaxf(as4[r] - ad4[r], 0.f);
        sc[r] = 0.5f * sc[r] + 0.25f * (rp + rm);
        dc[r] = 0.5f * dc[r] + 0.25f * (rp - rm);
      }
    }

    if (it < NITER - 1) {
      __syncthreads();   // all reads done before overwrite
      #pragma unroll
      for (int qd = 0; qd < 4; ++qd) {
        const int r = qd * 4;
        // lane writes state[mrow][nbase + 8*qd + 4*hi .. +3] per plane
        const int wb = sbase + ((((nt * 4 + qd)) ^ sw7) << 4) + hi * 8;
        *(uint2*)(lds + ZP_OFF + wb) =
            make_uint2(pk(zc[r + 1], zc[r]), pk(zc[r + 3], zc[r + 2]));
        f32x4 hi4, lo4;
        #pragma unroll
        for (int j = 0; j < 4; ++j) {
          hi4[j] = __uint_as_float(__float_as_uint(sc[r + j]) & 0xffff0000u);
          lo4[j] = sc[r + j] - hi4[j];
        }
        *(uint2*)(lds + SH_OFF + wb) = make_uint2(pk(hi4[1], hi4[0]), pk(hi4[3], hi4[2]));
        *(uint2*)(lds + SL_OFF + wb) = make_uint2(pk(lo4[1], lo4[0]), pk(lo4[3], lo4[2]));
        #pragma unroll
        for (int j = 0; j < 4; ++j) {
          hi4[j] = __uint_as_float(__float_as_uint(dc[r + j]) & 0xffff0000u);
          lo4[j] = dc[r + j] - hi4[j];
        }
        *(uint2*)(lds + DH_OFF + wb) = make_uint2(pk(hi4[1], hi4[0]), pk(hi4[3], hi4[2]));
        *(uint2*)(lds + DL_OFF + wb) = make_uint2(pk(lo4[1], lo4[0]), pk(lo4[3], lo4[2]));
      }
      __syncthreads();   // writes visible before next iteration
    }
  }

  // ---- store out: z / zh=s+d / zl=s-d ----
  const size_t PL = (size_t)B_ROWS * OUT_DIM;
  #pragma unroll
  for (int qd = 0; qd < 4; ++qd) {
    const int nb = nbase + qd * 8 + hi * 4;
    if (nb < OUT_DIM) {   // nb multiple of 4; quad fully valid iff nb < 100
      const int r = qd * 4;
      const size_t gi = (size_t)(r0 + mrow) * OUT_DIM + nb;
      f32x4 zv, hv, lv;
      #pragma unroll
      for (int j = 0; j < 4; ++j) {
        zv[j] = zc[r + j];
        hv[j] = sc[r + j] + dc[r + j];
        lv[j] = sc[r + j] - dc[r + j];
      }
      *(f32x4*)(out + gi)          = zv;
      *(f32x4*)(out + PL + gi)     = hv;
      *(f32x4*)(out + 2 * PL + gi) = lv;
    }
  }
}

extern "C" void kernel_launch(void* const* d_in, const int* in_sizes, int n_in,
                              void* d_out, int out_size, void* d_ws, size_t ws_size,
                              hipStream_t stream) {
  const float* x   = (const float*)d_in[0];
  const float* eps = (const float*)d_in[1];
  const float* A   = (const float*)d_in[2];
  const float* U   = (const float*)d_in[3];
  const float* b   = (const float*)d_in[4];
  float* out = (float*)d_out;

  unsigned* wsu  = (unsigned*)d_ws;
  float*    Wpad = (float*)d_ws + WPAD_F;
  float*    Upad = (float*)d_ws + UPAD_F;

  (void)hipFuncSetAttribute((const void*)k_main,
                            hipFuncAttributeMaxDynamicSharedMemorySize, LDS_TOTAL);

  k_init<<<1, 1, 0, stream>>>(wsu);
  k_minmax<<<1024, 256, 0, stream>>>((const float4*)x, wsu);
  k_wbuild<<<1, 128, 0, stream>>>(A, Wpad);
  k_upad<<<(128 * IN_DIM + 255) / 256, 256, 0, stream>>>(U, Upad);
  k_main<<<B_ROWS / RPB, TB, LDS_TOTAL, stream>>>(x, eps, b, Wpad, wsu, Upad, out);
}